// Round 14
// baseline (90.535 us; speedup 1.0000x reference)
//
#include <hip/hip_runtime.h>
#include <hip/hip_bf16.h>

#define N1   15996
#define N2   5328
#define NG2  5584
#define NJ   100
#define CLS  10
#define NMC  48      // m-chunks: 12 per channel
#define MCH  148     // 1776 = 12*148; 148 % 4 == 0 -> 16B-aligned float4 reads

// ---- KA: fused prep (conv1+dil1+conv2+dil2), per-block windowed recompute ----
__global__ __launch_bounds__(256)
void ka_prep(const float* __restrict__ x,  const float* __restrict__ w1,
             const float* __restrict__ b1, const float* __restrict__ t1,
             const float* __restrict__ w2, const float* __restrict__ b2,
             const float* __restrict__ t2, float* __restrict__ g2)
{
    __shared__ float Y1[804];
    __shared__ float G [800];
    __shared__ float Y2[264];
    const int tid = threadIdx.x;
    const int bid = blockIdx.x;

    int c, p0, cnt;
    if (bid < 21) { c = 0; p0 = bid * 256; cnt = (p0 + 256 <= N2) ? 256 : (N2 - p0); }
    else          { c = 1; p0 = 0;         cnt = 256; }

    const int q0 = (p0 - 3 > 0) ? p0 - 3 : 0;
    const int q1 = (p0 + cnt - 1 + 3 < N2 - 1) ? p0 + cnt - 1 + 3 : N2 - 1;
    const int nq = q1 - q0 + 1;
    const int g0 = 3 * q0, g1 = 3 * q1 + 13;
    const int ng = g1 - g0 + 1;
    const int h0 = (g0 - 3 > 0) ? g0 - 3 : 0;
    const int h1 = (g1 + 3 < N1 - 1) ? g1 + 3 : N1 - 1;
    const int nh = h1 - h0 + 1;

    for (int idx = tid; idx < nh; idx += 256) {
        const int n = h0 + idx;
        float acc = b1[0];
        #pragma unroll
        for (int k = 0; k < 5; ++k) acc += x[n + k] * w1[k];
        Y1[idx] = fmaxf(acc, 0.f);
    }
    __syncthreads();

    {
        const float it1 = 1.f / (4.f * t1[0]);
        for (int idx = tid; idx < ng; idx += 256) {
            const int n = g0 + idx;
            float m = -INFINITY;
            #pragma unroll
            for (int d = 0; d < 7; ++d) {
                int p = n + d - 3;
                if ((unsigned)p < (unsigned)N1) {
                    float z = (float)(d - 3);
                    m = fmaxf(m, Y1[p - h0] - z * z * it1);
                }
            }
            G[idx] = m;
        }
    }
    __syncthreads();

    for (int idx = tid; idx < nq; idx += 256) {
        const int q = q0 + idx;
        float acc = b2[c];
        #pragma unroll
        for (int k = 0; k < 5; ++k) {
            #pragma unroll
            for (int i = 0; i < 2; ++i)
                acc += G[i + 3 * (q + k) - g0] * w2[(c * 2 + i) * 5 + k];
        }
        Y2[idx] = fmaxf(acc, 0.f);
    }
    __syncthreads();

    {
        const float it2 = 1.f / (4.f * t2[c]);
        for (int idx = tid; idx < cnt; idx += 256) {
            const int p = p0 + idx;
            float m = -INFINITY;
            #pragma unroll
            for (int d = 0; d < 7; ++d) {
                int q = p + d - 3;
                if ((unsigned)q < (unsigned)N2) {
                    float z = (float)(d - 3);
                    m = fmaxf(m, Y2[q - q0] - z * z * it2);
                }
            }
            g2[c * N2 + p] = m;
        }
    }
}

// ---- KB: fc1 outer-product; W1 read directly from global (wave-uniform ->
// scalar s_load path, L2-resident); lane = batch; block = (bt, mc) ----
__global__ __launch_bounds__(256)
void kb_fc1(const float* __restrict__ g2, const float* __restrict__ W1,
            float* __restrict__ part)
{
    __shared__ float g2w[512];
    __shared__ float T[64 * NJ];      // 25.6 KB transpose buffer
    const int tid = threadIdx.x;
    const int bt  = blockIdx.x / NMC;      // 0..3
    const int mc  = blockIdx.x % NMC;      // 0..47

    const int c    = mc / 12;              // feature channel 0..3
    const int k0   = (mc % 12) * MCH;      // k offset within channel
    const int base = bt * 64 + c + 3 * k0; // flat g2 index of (local b=0, mi=0)

    for (int i = tid; i < 505; i += 256) {
        int gi = base + i;
        g2w[i] = (gi < NG2) ? g2[gi] : 0.f;   // max used = base + 63 + 3*147 <= 5583
    }
    __syncthreads();

    const int w = tid >> 6, l = tid & 63;  // wave w -> j in [25w,25w+25); lane = local batch
    float acc[25];
    #pragma unroll
    for (int jj = 0; jj < 25; ++jj) acc[jj] = 0.f;

    // uniform base: column index c*1776 + k0 is a multiple of 4 -> 16B aligned
    const float* wrow = W1 + (size_t)(w * 25) * 7104 + (c * 1776 + k0);

    for (int m4 = 0; m4 < 37; ++m4) {       // 148 = 37*4, no tail
        const int mi = 4 * m4;
        const float a0 = g2w[l + 3 * mi];
        const float a1 = g2w[l + 3 * mi + 3];
        const float a2 = g2w[l + 3 * mi + 6];
        const float a3 = g2w[l + 3 * mi + 9];
        #pragma unroll
        for (int jj = 0; jj < 25; ++jj) {
            const float4 wv = *reinterpret_cast<const float4*>(wrow + (size_t)jj * 7104 + mi);
            acc[jj] += a0 * wv.x + a1 * wv.y + a2 * wv.z + a3 * wv.w;
        }
    }

    #pragma unroll
    for (int jj = 0; jj < 25; ++jj)
        T[l * NJ + (w * 25 + jj)] = acc[jj];
    __syncthreads();

    // part[((bt*64+bl)*48 + mc)*100 + j] -- contiguous 100-float runs per (b,mc)
    for (int idx = tid; idx < 64 * NJ; idx += 256) {
        const int bl = idx / NJ, j = idx - bl * NJ;
        part[(size_t)((bt * 64 + bl) * NMC + mc) * NJ + j] = T[idx];
    }
}

// ---- KC: fused reduce + fc2 + log_softmax; block = batch row ----
__global__ __launch_bounds__(256)
void kc_out(const float* __restrict__ part, const float* __restrict__ fb1,
            const float* __restrict__ W2,  const float* __restrict__ fb2,
            float* __restrict__ out)
{
    __shared__ float S[NMC * NJ];    // 19.2 KB contiguous
    __shared__ float a1s[NJ];
    __shared__ float a2[CLS];
    const int tid = threadIdx.x;
    const int b   = blockIdx.x;

    const float* src = part + (size_t)b * NMC * NJ;
    for (int idx = tid; idx < NMC * NJ; idx += 256) S[idx] = src[idx];
    __syncthreads();

    if (tid < NJ) {
        float s = fb1[tid];
        #pragma unroll 8
        for (int mc = 0; mc < NMC; ++mc) s += S[mc * NJ + tid];
        a1s[tid] = fmaxf(s, 0.f);
    }
    __syncthreads();

    if (tid < CLS) {
        float acc = fb2[tid];
        #pragma unroll 4
        for (int j = 0; j < NJ; ++j) acc += a1s[j] * W2[tid * NJ + j];
        a2[tid] = acc;
    }
    __syncthreads();

    if (tid < CLS) {
        float mx = -INFINITY;
        #pragma unroll
        for (int n = 0; n < CLS; ++n) mx = fmaxf(mx, a2[n]);
        float s = 0.f;
        #pragma unroll
        for (int n = 0; n < CLS; ++n) s += expf(a2[n] - mx);
        out[b * CLS + tid] = a2[tid] - mx - logf(s);
    }
}

extern "C" void kernel_launch(void* const* d_in, const int* in_sizes, int n_in,
                              void* d_out, int out_size, void* d_ws, size_t ws_size,
                              hipStream_t stream)
{
    const float* x   = (const float*)d_in[0];
    const float* w1  = (const float*)d_in[1];
    const float* b1  = (const float*)d_in[2];
    const float* t1  = (const float*)d_in[3];
    const float* w2  = (const float*)d_in[4];
    const float* b2  = (const float*)d_in[5];
    const float* t2  = (const float*)d_in[6];
    const float* fw1 = (const float*)d_in[7];
    const float* fb1 = (const float*)d_in[8];
    const float* fw2 = (const float*)d_in[9];
    const float* fb2 = (const float*)d_in[10];

    float* ws   = (float*)d_ws;
    float* g2   = ws;                 // [NG2]
    float* part = ws + NG2;           // [256*48*100] = 4.9 MB

    ka_prep<<<22, 256, 0, stream>>>(x, w1, b1, t1, w2, b2, t2, g2);
    kb_fc1 <<<4 * NMC, 256, 0, stream>>>(g2, fw1, part);
    kc_out <<<256, 256, 0, stream>>>(part, fb1, fw2, fb2, (float*)d_out);
}

// Round 15
// 51.496 us; speedup vs baseline: 1.7581x; 1.7581x over previous
//
#include <hip/hip_runtime.h>
#include <hip/hip_bf16.h>

#define N1   15996
#define N2   5328
#define NG2  5584
#define NJ   100
#define CLS  10
#define NMC  192     // K chunks: 48 per feature channel
#define MCH  37      // 1776 = 48*37
#define MROW 40      // padded LDS row (160B, 16B-aligned)

// ---- KA: fused prep (conv1+dil1+conv2+dil2), per-block windowed recompute ----
// (unchanged from R13 — proven)
__global__ __launch_bounds__(256)
void ka_prep(const float* __restrict__ x,  const float* __restrict__ w1,
             const float* __restrict__ b1, const float* __restrict__ t1,
             const float* __restrict__ w2, const float* __restrict__ b2,
             const float* __restrict__ t2, float* __restrict__ g2)
{
    __shared__ float Y1[804];
    __shared__ float G [800];
    __shared__ float Y2[264];
    const int tid = threadIdx.x;
    const int bid = blockIdx.x;

    int c, p0, cnt;
    if (bid < 21) { c = 0; p0 = bid * 256; cnt = (p0 + 256 <= N2) ? 256 : (N2 - p0); }
    else          { c = 1; p0 = 0;         cnt = 256; }

    const int q0 = (p0 - 3 > 0) ? p0 - 3 : 0;
    const int q1 = (p0 + cnt - 1 + 3 < N2 - 1) ? p0 + cnt - 1 + 3 : N2 - 1;
    const int nq = q1 - q0 + 1;
    const int g0 = 3 * q0, g1 = 3 * q1 + 13;
    const int ng = g1 - g0 + 1;
    const int h0 = (g0 - 3 > 0) ? g0 - 3 : 0;
    const int h1 = (g1 + 3 < N1 - 1) ? g1 + 3 : N1 - 1;
    const int nh = h1 - h0 + 1;

    for (int idx = tid; idx < nh; idx += 256) {
        const int n = h0 + idx;
        float acc = b1[0];
        #pragma unroll
        for (int k = 0; k < 5; ++k) acc += x[n + k] * w1[k];
        Y1[idx] = fmaxf(acc, 0.f);
    }
    __syncthreads();

    {
        const float it1 = 1.f / (4.f * t1[0]);
        for (int idx = tid; idx < ng; idx += 256) {
            const int n = g0 + idx;
            float m = -INFINITY;
            #pragma unroll
            for (int d = 0; d < 7; ++d) {
                int p = n + d - 3;
                if ((unsigned)p < (unsigned)N1) {
                    float z = (float)(d - 3);
                    m = fmaxf(m, Y1[p - h0] - z * z * it1);
                }
            }
            G[idx] = m;
        }
    }
    __syncthreads();

    for (int idx = tid; idx < nq; idx += 256) {
        const int q = q0 + idx;
        float acc = b2[c];
        #pragma unroll
        for (int k = 0; k < 5; ++k) {
            #pragma unroll
            for (int i = 0; i < 2; ++i)
                acc += G[i + 3 * (q + k) - g0] * w2[(c * 2 + i) * 5 + k];
        }
        Y2[idx] = fmaxf(acc, 0.f);
    }
    __syncthreads();

    {
        const float it2 = 1.f / (4.f * t2[c]);
        for (int idx = tid; idx < cnt; idx += 256) {
            const int p = p0 + idx;
            float m = -INFINITY;
            #pragma unroll
            for (int d = 0; d < 7; ++d) {
                int q = p + d - 3;
                if ((unsigned)q < (unsigned)N2) {
                    float z = (float)(d - 3);
                    m = fmaxf(m, Y2[q - q0] - z * z * it2);
                }
            }
            g2[c * N2 + p] = m;
        }
    }
}

// ---- KB: fc1, register-blocked 25j x 4b per thread; block = one K-chunk ----
// block mc: c = mc/48, k0 = (mc%48)*37. Covers all 256 batches, 100 j, 37 k.
// One uniform W1 b128 read feeds 16 FMAs (4 k x 4 b).
__global__ __launch_bounds__(256)
void kb_fc1(const float* __restrict__ g2, const float* __restrict__ W1,
            float* __restrict__ part)
{
    __shared__ float LDS[25856];            // 103.4 KB union
    float* W1s = LDS;                       // [100*40]
    float* g2w = LDS + 24000;               // [368]
    const int tid = threadIdx.x;
    const int mc  = blockIdx.x;
    const int c   = mc / 48;
    const int k0  = (mc % 48) * MCH;
    const int base = c + 3 * k0;            // flat g2 index of (b=0, mi=0); <= 5220

    for (int idx = tid; idx < NJ * MCH; idx += 256) {
        const int j = idx / MCH, mi = idx % MCH;
        W1s[j * MROW + mi] = W1[(size_t)j * 7104 + c * 1776 + k0 + mi];
    }
    for (int i = tid; i < 368; i += 256) {
        const int gi = base + i;
        g2w[i] = (gi < NG2) ? g2[gi] : 0.f;  // max USED offset = 363 (<= 5583)
    }
    __syncthreads();

    const int w = tid >> 6, l = tid & 63;    // wave -> j in [25w,25w+25); lane -> b = l + 64m
    float acc[25][4];
    #pragma unroll
    for (int jj = 0; jj < 25; ++jj)
        #pragma unroll
        for (int m = 0; m < 4; ++m) acc[jj][m] = 0.f;

    const float* wbase = W1s + (w * 25) * MROW;
    for (int kq = 0; kq < 9; ++kq) {         // 37 = 9*4 + 1
        const int mi = 4 * kq;
        float a[4][4];
        #pragma unroll
        for (int m = 0; m < 4; ++m)
            #pragma unroll
            for (int s = 0; s < 4; ++s)
                a[m][s] = g2w[l + 64 * m + 3 * (mi + s)];
        #pragma unroll
        for (int jj = 0; jj < 25; ++jj) {
            const float4 wv = *reinterpret_cast<const float4*>(wbase + jj * MROW + mi);
            #pragma unroll
            for (int m = 0; m < 4; ++m)
                acc[jj][m] += a[m][0] * wv.x + a[m][1] * wv.y
                            + a[m][2] * wv.z + a[m][3] * wv.w;
        }
    }
    {   // tail k: mi = 36
        float a[4];
        #pragma unroll
        for (int m = 0; m < 4; ++m) a[m] = g2w[l + 64 * m + 108];
        #pragma unroll
        for (int jj = 0; jj < 25; ++jj) {
            const float wv = wbase[jj * MROW + 36];
            #pragma unroll
            for (int m = 0; m < 4; ++m) acc[jj][m] += a[m] * wv;
        }
    }
    __syncthreads();                         // W1s/g2w dead; reuse LDS as T

    float* T = LDS;                          // [256][101] padded (stride 101: conflict-free)
    #pragma unroll
    for (int jj = 0; jj < 25; ++jj)
        #pragma unroll
        for (int m = 0; m < 4; ++m)
            T[(l + 64 * m) * 101 + (w * 25 + jj)] = acc[jj][m];
    __syncthreads();

    // part[(b*192 + mc)*100 + j] : contiguous 100-float run per (b, mc)
    for (int idx = tid; idx < 256 * NJ; idx += 256) {
        const int b = idx / NJ, j = idx - b * NJ;
        part[((size_t)b * NMC + mc) * NJ + j] = T[b * 101 + j];
    }
}

// ---- KC: reduce 192 chunks + fc2 + log_softmax; block = batch ----
__global__ __launch_bounds__(256)
void kc_out(const float* __restrict__ part, const float* __restrict__ fb1,
            const float* __restrict__ W2,  const float* __restrict__ fb2,
            float* __restrict__ out)
{
    __shared__ float S[NMC * NJ];    // 76.8 KB, contiguous per batch
    __shared__ float a1s[NJ];
    __shared__ float a2[CLS];
    const int tid = threadIdx.x;
    const int b   = blockIdx.x;

    const float* src = part + (size_t)b * NMC * NJ;
    for (int idx = tid; idx < NMC * NJ; idx += 256) S[idx] = src[idx];
    __syncthreads();

    if (tid < NJ) {
        float s = fb1[tid];
        #pragma unroll 8
        for (int mc = 0; mc < NMC; ++mc) s += S[mc * NJ + tid];
        a1s[tid] = fmaxf(s, 0.f);
    }
    __syncthreads();

    if (tid < CLS) {
        float acc = fb2[tid];
        #pragma unroll 4
        for (int j = 0; j < NJ; ++j) acc += a1s[j] * W2[tid * NJ + j];
        a2[tid] = acc;
    }
    __syncthreads();

    if (tid < CLS) {
        float mx = -INFINITY;
        #pragma unroll
        for (int n = 0; n < CLS; ++n) mx = fmaxf(mx, a2[n]);
        float s = 0.f;
        #pragma unroll
        for (int n = 0; n < CLS; ++n) s += expf(a2[n] - mx);
        out[b * CLS + tid] = a2[tid] - mx - logf(s);
    }
}

extern "C" void kernel_launch(void* const* d_in, const int* in_sizes, int n_in,
                              void* d_out, int out_size, void* d_ws, size_t ws_size,
                              hipStream_t stream)
{
    const float* x   = (const float*)d_in[0];
    const float* w1  = (const float*)d_in[1];
    const float* b1  = (const float*)d_in[2];
    const float* t1  = (const float*)d_in[3];
    const float* w2  = (const float*)d_in[4];
    const float* b2  = (const float*)d_in[5];
    const float* t2  = (const float*)d_in[6];
    const float* fw1 = (const float*)d_in[7];
    const float* fb1 = (const float*)d_in[8];
    const float* fw2 = (const float*)d_in[9];
    const float* fb2 = (const float*)d_in[10];

    float* ws   = (float*)d_ws;
    float* g2   = ws;                 // [NG2]
    float* part = ws + NG2;           // [256*192*100] = 19.7 MB

    ka_prep<<<22, 256, 0, stream>>>(x, w1, b1, t1, w2, b2, t2, g2);
    kb_fc1 <<<NMC, 256, 0, stream>>>(g2, fw1, part);
    kc_out <<<256, 256, 0, stream>>>(part, fb1, fw2, fb2, (float*)d_out);
}

// Round 16
// 42.051 us; speedup vs baseline: 2.1530x; 1.2246x over previous
//
#include <hip/hip_runtime.h>
#include <hip/hip_bf16.h>

#define N1   15996
#define N2   5328
#define NG2  5584
#define NJ   100
#define CLS  10
#define NMC  96      // K chunks: 24 per feature channel
#define MCH  74      // 1776 = 24*74
#define MROW 76      // padded LDS row: 304B, 16B-aligned
#define LDSF 13056   // union floats: max(100*76+348, 128*101=12928)

// ---- KA: fused prep (conv1+dil1+conv2+dil2), per-block windowed recompute ----
// (unchanged from R13 — proven)
__global__ __launch_bounds__(256)
void ka_prep(const float* __restrict__ x,  const float* __restrict__ w1,
             const float* __restrict__ b1, const float* __restrict__ t1,
             const float* __restrict__ w2, const float* __restrict__ b2,
             const float* __restrict__ t2, float* __restrict__ g2)
{
    __shared__ float Y1[804];
    __shared__ float G [800];
    __shared__ float Y2[264];
    const int tid = threadIdx.x;
    const int bid = blockIdx.x;

    int c, p0, cnt;
    if (bid < 21) { c = 0; p0 = bid * 256; cnt = (p0 + 256 <= N2) ? 256 : (N2 - p0); }
    else          { c = 1; p0 = 0;         cnt = 256; }

    const int q0 = (p0 - 3 > 0) ? p0 - 3 : 0;
    const int q1 = (p0 + cnt - 1 + 3 < N2 - 1) ? p0 + cnt - 1 + 3 : N2 - 1;
    const int nq = q1 - q0 + 1;
    const int g0 = 3 * q0, g1 = 3 * q1 + 13;
    const int ng = g1 - g0 + 1;
    const int h0 = (g0 - 3 > 0) ? g0 - 3 : 0;
    const int h1 = (g1 + 3 < N1 - 1) ? g1 + 3 : N1 - 1;
    const int nh = h1 - h0 + 1;

    for (int idx = tid; idx < nh; idx += 256) {
        const int n = h0 + idx;
        float acc = b1[0];
        #pragma unroll
        for (int k = 0; k < 5; ++k) acc += x[n + k] * w1[k];
        Y1[idx] = fmaxf(acc, 0.f);
    }
    __syncthreads();

    {
        const float it1 = 1.f / (4.f * t1[0]);
        for (int idx = tid; idx < ng; idx += 256) {
            const int n = g0 + idx;
            float m = -INFINITY;
            #pragma unroll
            for (int d = 0; d < 7; ++d) {
                int p = n + d - 3;
                if ((unsigned)p < (unsigned)N1) {
                    float z = (float)(d - 3);
                    m = fmaxf(m, Y1[p - h0] - z * z * it1);
                }
            }
            G[idx] = m;
        }
    }
    __syncthreads();

    for (int idx = tid; idx < nq; idx += 256) {
        const int q = q0 + idx;
        float acc = b2[c];
        #pragma unroll
        for (int k = 0; k < 5; ++k) {
            #pragma unroll
            for (int i = 0; i < 2; ++i)
                acc += G[i + 3 * (q + k) - g0] * w2[(c * 2 + i) * 5 + k];
        }
        Y2[idx] = fmaxf(acc, 0.f);
    }
    __syncthreads();

    {
        const float it2 = 1.f / (4.f * t2[c]);
        for (int idx = tid; idx < cnt; idx += 256) {
            const int p = p0 + idx;
            float m = -INFINITY;
            #pragma unroll
            for (int d = 0; d < 7; ++d) {
                int q = p + d - 3;
                if ((unsigned)q < (unsigned)N2) {
                    float z = (float)(d - 3);
                    m = fmaxf(m, Y2[q - q0] - z * z * it2);
                }
            }
            g2[c * N2 + p] = m;
        }
    }
}

// ---- KB: fc1, 25j x 2-batch register block; block = (bt, mc); grid 192 ----
// One uniform W1 b128 read feeds 8 FMAs (4 k x 2 b).
__global__ __launch_bounds__(256)
void kb_fc1(const float* __restrict__ g2, const float* __restrict__ W1,
            float* __restrict__ part)
{
    __shared__ float LDS[LDSF];             // 52.2 KB union
    float* W1s = LDS;                       // [100*76]
    float* g2w = LDS + 7600;                // [348]
    const int tid = threadIdx.x;
    const int bt  = blockIdx.x / NMC;       // 0..1 (128-batch tile)
    const int mc  = blockIdx.x % NMC;       // 0..95
    const int c   = mc / 24;
    const int k0  = (mc % 24) * MCH;
    const int base = bt * 128 + c + 3 * k0; // max used = base+346 <= 5583

    for (int idx = tid; idx < NJ * MCH; idx += 256) {
        const int j = idx / MCH, mi = idx % MCH;
        W1s[j * MROW + mi] = W1[(size_t)j * 7104 + c * 1776 + k0 + mi];
    }
    for (int i = tid; i < 348; i += 256) {
        const int gi = base + i;
        g2w[i] = (gi < NG2) ? g2[gi] : 0.f;
    }
    __syncthreads();

    const int w = tid >> 6, l = tid & 63;   // wave -> j in [25w,25w+25); lane -> b = bt*128 + l + 64m
    float acc[25][2];
    #pragma unroll
    for (int jj = 0; jj < 25; ++jj) { acc[jj][0] = 0.f; acc[jj][1] = 0.f; }

    const float* wbase = W1s + (w * 25) * MROW;
    for (int kq = 0; kq < 18; ++kq) {       // 74 = 18*4 + 2
        const int mi = 4 * kq;
        float a[2][4];
        #pragma unroll
        for (int m = 0; m < 2; ++m)
            #pragma unroll
            for (int s = 0; s < 4; ++s)
                a[m][s] = g2w[l + 64 * m + 3 * (mi + s)];
        #pragma unroll
        for (int jj = 0; jj < 25; ++jj) {
            const float4 wv = *reinterpret_cast<const float4*>(wbase + jj * MROW + mi);
            #pragma unroll
            for (int m = 0; m < 2; ++m)
                acc[jj][m] += a[m][0] * wv.x + a[m][1] * wv.y
                            + a[m][2] * wv.z + a[m][3] * wv.w;
        }
    }
    #pragma unroll
    for (int s = 72; s < 74; ++s) {         // tail k
        float a0 = g2w[l + 3 * s], a1 = g2w[l + 64 + 3 * s];
        #pragma unroll
        for (int jj = 0; jj < 25; ++jj) {
            const float wv = wbase[jj * MROW + s];
            acc[jj][0] += a0 * wv;
            acc[jj][1] += a1 * wv;
        }
    }
    __syncthreads();                        // staging dead; reuse LDS as T

    float* T = LDS;                         // [128][101] padded (conflict-free)
    #pragma unroll
    for (int jj = 0; jj < 25; ++jj) {
        T[l * 101 + (w * 25 + jj)]        = acc[jj][0];
        T[(l + 64) * 101 + (w * 25 + jj)] = acc[jj][1];
    }
    __syncthreads();

    // part[(b*96 + mc)*100 + j] : contiguous 100-float run per (b, mc)
    for (int idx = tid; idx < 128 * NJ; idx += 256) {
        const int bl = idx / NJ, j = idx - bl * NJ;
        part[((size_t)(bt * 128 + bl) * NMC + mc) * NJ + j] = T[bl * 101 + j];
    }
}

// ---- KC: reduce 96 chunks + fc2 + log_softmax; block = batch ----
__global__ __launch_bounds__(256)
void kc_out(const float* __restrict__ part, const float* __restrict__ fb1,
            const float* __restrict__ W2,  const float* __restrict__ fb2,
            float* __restrict__ out)
{
    __shared__ float S[NMC * NJ];    // 38.4 KB contiguous
    __shared__ float a1s[NJ];
    __shared__ float a2[CLS];
    const int tid = threadIdx.x;
    const int b   = blockIdx.x;

    const float* src = part + (size_t)b * NMC * NJ;
    for (int idx = tid; idx < NMC * NJ; idx += 256) S[idx] = src[idx];
    __syncthreads();

    if (tid < NJ) {
        float s = fb1[tid];
        #pragma unroll 8
        for (int mc = 0; mc < NMC; ++mc) s += S[mc * NJ + tid];
        a1s[tid] = fmaxf(s, 0.f);
    }
    __syncthreads();

    if (tid < CLS) {
        float acc = fb2[tid];
        #pragma unroll 4
        for (int j = 0; j < NJ; ++j) acc += a1s[j] * W2[tid * NJ + j];
        a2[tid] = acc;
    }
    __syncthreads();

    if (tid < CLS) {
        float mx = -INFINITY;
        #pragma unroll
        for (int n = 0; n < CLS; ++n) mx = fmaxf(mx, a2[n]);
        float s = 0.f;
        #pragma unroll
        for (int n = 0; n < CLS; ++n) s += expf(a2[n] - mx);
        out[b * CLS + tid] = a2[tid] - mx - logf(s);
    }
}

extern "C" void kernel_launch(void* const* d_in, const int* in_sizes, int n_in,
                              void* d_out, int out_size, void* d_ws, size_t ws_size,
                              hipStream_t stream)
{
    const float* x   = (const float*)d_in[0];
    const float* w1  = (const float*)d_in[1];
    const float* b1  = (const float*)d_in[2];
    const float* t1  = (const float*)d_in[3];
    const float* w2  = (const float*)d_in[4];
    const float* b2  = (const float*)d_in[5];
    const float* t2  = (const float*)d_in[6];
    const float* fw1 = (const float*)d_in[7];
    const float* fb1 = (const float*)d_in[8];
    const float* fw2 = (const float*)d_in[9];
    const float* fb2 = (const float*)d_in[10];

    float* ws   = (float*)d_ws;
    float* g2   = ws;                 // [NG2]
    float* part = ws + NG2;           // [256*96*100] = 9.8 MB

    ka_prep<<<22, 256, 0, stream>>>(x, w1, b1, t1, w2, b2, t2, g2);
    kb_fc1 <<<2 * NMC, 256, 0, stream>>>(g2, fw1, part);
    kc_out <<<256, 256, 0, stream>>>(part, fb1, fw2, fb2, (float*)d_out);
}

// Round 17
// 40.761 us; speedup vs baseline: 2.2211x; 1.0316x over previous
//
#include <hip/hip_runtime.h>
#include <hip/hip_bf16.h>

#define N1   15996
#define N2   5328
#define NG2  5584
#define NJ   100
#define CLS  10
#define NMC  96      // K chunks: 24 per feature channel
#define MCH  74      // 1776 = 24*74
#define MROW 76      // padded LDS row: 304B, 16B-aligned
#define LDSF 13056   // floats: max(10460 staging, 128*101=12928 transpose)

// LDS float offsets
#define OFF_G2W 7600    // [348]
#define OFF_Y1  7948    // [1082]
#define OFF_G   9030    // [1076]
#define OFF_Y2  10106   // [354]

// ---- KB: fused prep + fc1 ----
// Block (bt, mc): recomputes g2 window [base, base+347] from x via the
// windowed chain conv1->dil1->conv2->dil2 (per-channel segments), then the
// proven 25j x 2-batch register-blocked MAC.
__global__ __launch_bounds__(256)
void kb_fused(const float* __restrict__ x,  const float* __restrict__ w1,
              const float* __restrict__ b1, const float* __restrict__ t1,
              const float* __restrict__ w2, const float* __restrict__ b2,
              const float* __restrict__ t2, const float* __restrict__ W1,
              float* __restrict__ part)
{
    __shared__ float LDS[LDSF];
    float* W1s = LDS;
    float* g2w = LDS + OFF_G2W;
    float* Y1  = LDS + OFF_Y1;
    float* G   = LDS + OFF_G;
    float* Y2  = LDS + OFF_Y2;
    const int tid = threadIdx.x;
    const int bt  = blockIdx.x / NMC;
    const int mc  = blockIdx.x % NMC;
    const int c   = mc / 24;
    const int k0  = (mc % 24) * MCH;
    const int base = bt * 128 + c + 3 * k0;          // <= 5237
    const int jhi  = (base + 347 <= NG2 - 1) ? base + 347 : NG2 - 1;

    // ---- stage W1 chunk + zero g2w ----
    for (int idx = tid; idx < NJ * MCH; idx += 256) {
        const int j = idx / MCH, mi = idx % MCH;
        W1s[j * MROW + mi] = W1[(size_t)j * 7104 + c * 1776 + k0 + mi];
    }
    for (int i = tid; i < 348; i += 256) g2w[i] = 0.f;

    // ---- prep segments: A = channel 0 part, B = channel 1 part (if any) ----
    const float it1 = 1.f / (4.f * t1[0]);
    const bool hasB = (jhi >= N2);
    #pragma unroll 1
    for (int seg = 0; seg < 2; ++seg) {
        if (seg == 1 && !hasB) break;
        int ch, plo, phi, doff;
        if (seg == 0) { ch = 0; plo = base; phi = (jhi < N2 - 1) ? jhi : N2 - 1; doff = 0; }
        else          { ch = 1; plo = 0;    phi = jhi - N2;                      doff = N2 - base; }

        const int qa = (plo - 3 > 0) ? plo - 3 : 0;
        const int qb = (phi + 3 < N2 - 1) ? phi + 3 : N2 - 1;
        const int nq = qb - qa + 1;                  // <= 354
        const int ga = 3 * qa, gb = 3 * qb + 13;     // gb <= 15994
        const int ng = gb - ga + 1;                  // <= 1076
        const int ha = (ga - 3 > 0) ? ga - 3 : 0;
        const int hb = (gb + 3 < N1 - 1) ? gb + 3 : N1 - 1;
        const int nh = hb - ha + 1;                  // <= 1082

        __syncthreads();   // protect Y1/G/Y2 reuse across segments
        for (int idx = tid; idx < nh; idx += 256) {
            const int n = ha + idx;
            float acc = b1[0];
            #pragma unroll
            for (int k = 0; k < 5; ++k) acc += x[n + k] * w1[k];
            Y1[idx] = fmaxf(acc, 0.f);
        }
        __syncthreads();
        for (int idx = tid; idx < ng; idx += 256) {
            const int n = ga + idx;
            float m = -INFINITY;
            #pragma unroll
            for (int d = 0; d < 7; ++d) {
                int p = n + d - 3;
                if ((unsigned)p < (unsigned)N1) {
                    float z = (float)(d - 3);
                    m = fmaxf(m, Y1[p - ha] - z * z * it1);
                }
            }
            G[idx] = m;
        }
        __syncthreads();
        for (int idx = tid; idx < nq; idx += 256) {
            const int q = qa + idx;
            float acc = b2[ch];
            #pragma unroll
            for (int k = 0; k < 5; ++k) {
                #pragma unroll
                for (int i = 0; i < 2; ++i)
                    acc += G[i + 3 * (q + k) - ga] * w2[(ch * 2 + i) * 5 + k];
            }
            Y2[idx] = fmaxf(acc, 0.f);
        }
        __syncthreads();
        {
            const float it2 = 1.f / (4.f * t2[ch]);
            for (int idx = tid; idx <= phi - plo; idx += 256) {
                const int p = plo + idx;
                float m = -INFINITY;
                #pragma unroll
                for (int d = 0; d < 7; ++d) {
                    int q = p + d - 3;
                    if ((unsigned)q < (unsigned)N2) {
                        float z = (float)(d - 3);
                        m = fmaxf(m, Y2[q - qa] - z * z * it2);
                    }
                }
                g2w[doff + idx] = m;
            }
        }
    }
    __syncthreads();   // g2w + W1s ready

    // ---- MAC: 25 j x 2 batches per thread (proven R16 loop) ----
    const int w = tid >> 6, l = tid & 63;
    float acc[25][2];
    #pragma unroll
    for (int jj = 0; jj < 25; ++jj) { acc[jj][0] = 0.f; acc[jj][1] = 0.f; }

    const float* wbase = W1s + (w * 25) * MROW;
    for (int kq = 0; kq < 18; ++kq) {
        const int mi = 4 * kq;
        float a[2][4];
        #pragma unroll
        for (int m = 0; m < 2; ++m)
            #pragma unroll
            for (int s = 0; s < 4; ++s)
                a[m][s] = g2w[l + 64 * m + 3 * (mi + s)];
        #pragma unroll
        for (int jj = 0; jj < 25; ++jj) {
            const float4 wv = *reinterpret_cast<const float4*>(wbase + jj * MROW + mi);
            #pragma unroll
            for (int m = 0; m < 2; ++m)
                acc[jj][m] += a[m][0] * wv.x + a[m][1] * wv.y
                            + a[m][2] * wv.z + a[m][3] * wv.w;
        }
    }
    #pragma unroll
    for (int s = 72; s < 74; ++s) {
        float a0 = g2w[l + 3 * s], a1 = g2w[l + 64 + 3 * s];
        #pragma unroll
        for (int jj = 0; jj < 25; ++jj) {
            const float wv = wbase[jj * MROW + s];
            acc[jj][0] += a0 * wv;
            acc[jj][1] += a1 * wv;
        }
    }
    __syncthreads();   // staging dead; reuse LDS as T

    float* T = LDS;    // [128][101] padded (conflict-free)
    #pragma unroll
    for (int jj = 0; jj < 25; ++jj) {
        T[l * 101 + (w * 25 + jj)]        = acc[jj][0];
        T[(l + 64) * 101 + (w * 25 + jj)] = acc[jj][1];
    }
    __syncthreads();

    for (int idx = tid; idx < 128 * NJ; idx += 256) {
        const int bl = idx / NJ, j = idx - bl * NJ;
        part[((size_t)(bt * 128 + bl) * NMC + mc) * NJ + j] = T[bl * 101 + j];
    }
}

// ---- KC: reduce 96 chunks + fc2 + log_softmax; block = batch ----
__global__ __launch_bounds__(256)
void kc_out(const float* __restrict__ part, const float* __restrict__ fb1,
            const float* __restrict__ W2,  const float* __restrict__ fb2,
            float* __restrict__ out)
{
    __shared__ float S[NMC * NJ];    // 38.4 KB contiguous
    __shared__ float a1s[NJ];
    __shared__ float a2[CLS];
    const int tid = threadIdx.x;
    const int b   = blockIdx.x;

    const float* src = part + (size_t)b * NMC * NJ;
    for (int idx = tid; idx < NMC * NJ; idx += 256) S[idx] = src[idx];
    __syncthreads();

    if (tid < NJ) {
        float s = fb1[tid];
        #pragma unroll 8
        for (int mc = 0; mc < NMC; ++mc) s += S[mc * NJ + tid];
        a1s[tid] = fmaxf(s, 0.f);
    }
    __syncthreads();

    if (tid < CLS) {
        float acc = fb2[tid];
        #pragma unroll 4
        for (int j = 0; j < NJ; ++j) acc += a1s[j] * W2[tid * NJ + j];
        a2[tid] = acc;
    }
    __syncthreads();

    if (tid < CLS) {
        float mx = -INFINITY;
        #pragma unroll
        for (int n = 0; n < CLS; ++n) mx = fmaxf(mx, a2[n]);
        float s = 0.f;
        #pragma unroll
        for (int n = 0; n < CLS; ++n) s += expf(a2[n] - mx);
        out[b * CLS + tid] = a2[tid] - mx - logf(s);
    }
}

extern "C" void kernel_launch(void* const* d_in, const int* in_sizes, int n_in,
                              void* d_out, int out_size, void* d_ws, size_t ws_size,
                              hipStream_t stream)
{
    const float* x   = (const float*)d_in[0];
    const float* w1  = (const float*)d_in[1];
    const float* b1  = (const float*)d_in[2];
    const float* t1  = (const float*)d_in[3];
    const float* w2  = (const float*)d_in[4];
    const float* b2  = (const float*)d_in[5];
    const float* t2  = (const float*)d_in[6];
    const float* fw1 = (const float*)d_in[7];
    const float* fb1 = (const float*)d_in[8];
    const float* fw2 = (const float*)d_in[9];
    const float* fb2 = (const float*)d_in[10];

    float* part = (float*)d_ws;       // [256*96*100] = 9.8 MB

    kb_fused<<<2 * NMC, 256, 0, stream>>>(x, w1, b1, t1, w2, b2, t2, fw1, part);
    kc_out  <<<256, 256, 0, stream>>>(part, fb1, fw2, fb2, (float*)d_out);
}

// Round 18
// 32.370 us; speedup vs baseline: 2.7969x; 1.2592x over previous
//
#include <hip/hip_runtime.h>
#include <hip/hip_bf16.h>
#include <hip/hip_fp16.h>

#define N1   15996
#define N2   5328
#define NG2  5584
#define NJ   100
#define CLS  10
#define NMC  96      // K chunks: 24 per feature channel
#define MCH  74      // 1776 = 24*74
#define PAIRS 37     // 74/2 k-pairs
#define WRU  40      // W1 LDS row stride in u32 (160B, 16B-aligned)
#define LDSF 12928   // floats: max(7208 staging, 128*101=12928 transpose)

// LDS layout (float/u32 indices)
#define OFF_GP  4000    // u32 [344]
#define OFF_G2W 4348    // f32 [348]
#define OFF_Y1  4696    // f32 [1082]
#define OFF_G   5778    // f32 [1076]
#define OFF_Y2  6854    // f32 [354]

typedef _Float16 h2v __attribute__((ext_vector_type(2)));

static __device__ __forceinline__ unsigned pack2(float a, float b) {
    union { h2v v; unsigned u; } U;
    U.v[0] = (_Float16)a; U.v[1] = (_Float16)b;
    return U.u;
}

static __device__ __forceinline__ float dot2(unsigned wu, unsigned gu, float c) {
    union { unsigned u; h2v v; } W, G;
    W.u = wu; G.u = gu;
#if __has_builtin(__builtin_amdgcn_fdot2)
    return __builtin_amdgcn_fdot2(W.v, G.v, c, false);
#else
    return c + (float)W.v[0] * (float)G.v[0] + (float)W.v[1] * (float)G.v[1];
#endif
}

// ---- KB: fused prep + fc1 (f16 dot2 MAC) ----
__global__ __launch_bounds__(256)
void kb_fused(const float* __restrict__ x,  const float* __restrict__ w1,
              const float* __restrict__ b1, const float* __restrict__ t1,
              const float* __restrict__ w2, const float* __restrict__ b2,
              const float* __restrict__ t2, const float* __restrict__ W1,
              float* __restrict__ part)
{
    __shared__ float LDS[LDSF];
    unsigned* W1u = (unsigned*)LDS;          // [100*40] packed f16 pairs
    unsigned* gpu = (unsigned*)LDS + OFF_GP; // [344] packed (g[i], g[i+3])
    float* g2w = LDS + OFF_G2W;
    float* Y1  = LDS + OFF_Y1;
    float* G   = LDS + OFF_G;
    float* Y2  = LDS + OFF_Y2;
    const int tid = threadIdx.x;
    const int bt  = blockIdx.x / NMC;
    const int mc  = blockIdx.x % NMC;
    const int c   = mc / 24;
    const int k0  = (mc % 24) * MCH;
    const int base = bt * 128 + c + 3 * k0;          // <= 5237
    const int jhi  = (base + 347 <= NG2 - 1) ? base + 347 : NG2 - 1;

    // ---- stage W1 chunk as packed f16 pairs (coalesced float2 reads) ----
    for (int idx = tid; idx < NJ * PAIRS; idx += 256) {
        const int j = idx / PAIRS, p = idx % PAIRS;
        const float2 r = *reinterpret_cast<const float2*>(
            W1 + (size_t)j * 7104 + c * 1776 + k0 + 2 * p);
        W1u[j * WRU + p] = pack2(r.x, r.y);
    }
    for (int i = tid; i < 348; i += 256) g2w[i] = 0.f;

    // ---- prep segments (verified R17 logic) ----
    const float it1 = 1.f / (4.f * t1[0]);
    const bool hasB = (jhi >= N2);
    #pragma unroll 1
    for (int seg = 0; seg < 2; ++seg) {
        if (seg == 1 && !hasB) break;
        int ch, plo, phi, doff;
        if (seg == 0) { ch = 0; plo = base; phi = (jhi < N2 - 1) ? jhi : N2 - 1; doff = 0; }
        else          { ch = 1; plo = 0;    phi = jhi - N2;                      doff = N2 - base; }

        const int qa = (plo - 3 > 0) ? plo - 3 : 0;
        const int qb = (phi + 3 < N2 - 1) ? phi + 3 : N2 - 1;
        const int nq = qb - qa + 1;
        const int ga = 3 * qa, gb = 3 * qb + 13;
        const int ng = gb - ga + 1;
        const int ha = (ga - 3 > 0) ? ga - 3 : 0;
        const int hb = (gb + 3 < N1 - 1) ? gb + 3 : N1 - 1;
        const int nh = hb - ha + 1;

        __syncthreads();
        for (int idx = tid; idx < nh; idx += 256) {
            const int n = ha + idx;
            float acc = b1[0];
            #pragma unroll
            for (int k = 0; k < 5; ++k) acc += x[n + k] * w1[k];
            Y1[idx] = fmaxf(acc, 0.f);
        }
        __syncthreads();
        for (int idx = tid; idx < ng; idx += 256) {
            const int n = ga + idx;
            float m = -INFINITY;
            #pragma unroll
            for (int d = 0; d < 7; ++d) {
                int p = n + d - 3;
                if ((unsigned)p < (unsigned)N1) {
                    float z = (float)(d - 3);
                    m = fmaxf(m, Y1[p - ha] - z * z * it1);
                }
            }
            G[idx] = m;
        }
        __syncthreads();
        for (int idx = tid; idx < nq; idx += 256) {
            const int q = qa + idx;
            float acc = b2[ch];
            #pragma unroll
            for (int k = 0; k < 5; ++k) {
                #pragma unroll
                for (int i = 0; i < 2; ++i)
                    acc += G[i + 3 * (q + k) - ga] * w2[(ch * 2 + i) * 5 + k];
            }
            Y2[idx] = fmaxf(acc, 0.f);
        }
        __syncthreads();
        {
            const float it2 = 1.f / (4.f * t2[ch]);
            for (int idx = tid; idx <= phi - plo; idx += 256) {
                const int p = plo + idx;
                float m = -INFINITY;
                #pragma unroll
                for (int d = 0; d < 7; ++d) {
                    int q = p + d - 3;
                    if ((unsigned)q < (unsigned)N2) {
                        float z = (float)(d - 3);
                        m = fmaxf(m, Y2[q - qa] - z * z * it2);
                    }
                }
                g2w[doff + idx] = m;
            }
        }
    }
    __syncthreads();   // g2w complete

    // ---- pack gp[i] = (g2w[i], g2w[i+3]) as f16 pair ----
    for (int i = tid; i < 344; i += 256) gpu[i] = pack2(g2w[i], g2w[i + 3]);
    __syncthreads();

    // ---- MAC: 25 j x 2 batches per thread, f16 dot2 ----
    const int w = tid >> 6, l = tid & 63;
    float acc[25][2];
    #pragma unroll
    for (int jj = 0; jj < 25; ++jj) { acc[jj][0] = 0.f; acc[jj][1] = 0.f; }

    const unsigned* wrow = W1u + (w * 25) * WRU;
    for (int kq = 0; kq < 9; ++kq) {          // 37 pairs = 9*4 + 1
        unsigned a[2][4];
        #pragma unroll
        for (int m = 0; m < 2; ++m)
            #pragma unroll
            for (int t = 0; t < 4; ++t)
                a[m][t] = gpu[l + 64 * m + 24 * kq + 6 * t];
        #pragma unroll
        for (int jj = 0; jj < 25; ++jj) {
            const uint4 wv = *reinterpret_cast<const uint4*>(wrow + jj * WRU + 4 * kq);
            #pragma unroll
            for (int m = 0; m < 2; ++m) {
                float s = acc[jj][m];
                s = dot2(wv.x, a[m][0], s);
                s = dot2(wv.y, a[m][1], s);
                s = dot2(wv.z, a[m][2], s);
                s = dot2(wv.w, a[m][3], s);
                acc[jj][m] = s;
            }
        }
    }
    {   // tail pair s = 36
        unsigned a0 = gpu[l + 216], a1v = gpu[l + 64 + 216];
        #pragma unroll
        for (int jj = 0; jj < 25; ++jj) {
            const unsigned wt = wrow[jj * WRU + 36];
            acc[jj][0] = dot2(wt, a0, acc[jj][0]);
            acc[jj][1] = dot2(wt, a1v, acc[jj][1]);
        }
    }
    __syncthreads();   // staging dead; reuse LDS as T

    float* T = LDS;    // [128][101] padded (conflict-free)
    #pragma unroll
    for (int jj = 0; jj < 25; ++jj) {
        T[l * 101 + (w * 25 + jj)]        = acc[jj][0];
        T[(l + 64) * 101 + (w * 25 + jj)] = acc[jj][1];
    }
    __syncthreads();

    for (int idx = tid; idx < 128 * NJ; idx += 256) {
        const int bl = idx / NJ, j = idx - bl * NJ;
        part[((size_t)(bt * 128 + bl) * NMC + mc) * NJ + j] = T[bl * 101 + j];
    }
}

// ---- KC: reduce 96 chunks + fc2 + log_softmax; block = batch ----
__global__ __launch_bounds__(256)
void kc_out(const float* __restrict__ part, const float* __restrict__ fb1,
            const float* __restrict__ W2,  const float* __restrict__ fb2,
            float* __restrict__ out)
{
    __shared__ float S[NMC * NJ];    // 38.4 KB contiguous
    __shared__ float a1s[NJ];
    __shared__ float a2[CLS];
    const int tid = threadIdx.x;
    const int b   = blockIdx.x;

    const float* src = part + (size_t)b * NMC * NJ;
    for (int idx = tid; idx < NMC * NJ; idx += 256) S[idx] = src[idx];
    __syncthreads();

    if (tid < NJ) {
        float s = fb1[tid];
        #pragma unroll 8
        for (int mc = 0; mc < NMC; ++mc) s += S[mc * NJ + tid];
        a1s[tid] = fmaxf(s, 0.f);
    }
    __syncthreads();

    if (tid < CLS) {
        float acc = fb2[tid];
        #pragma unroll 4
        for (int j = 0; j < NJ; ++j) acc += a1s[j] * W2[tid * NJ + j];
        a2[tid] = acc;
    }
    __syncthreads();

    if (tid < CLS) {
        float mx = -INFINITY;
        #pragma unroll
        for (int n = 0; n < CLS; ++n) mx = fmaxf(mx, a2[n]);
        float s = 0.f;
        #pragma unroll
        for (int n = 0; n < CLS; ++n) s += expf(a2[n] - mx);
        out[b * CLS + tid] = a2[tid] - mx - logf(s);
    }
}

extern "C" void kernel_launch(void* const* d_in, const int* in_sizes, int n_in,
                              void* d_out, int out_size, void* d_ws, size_t ws_size,
                              hipStream_t stream)
{
    const float* x   = (const float*)d_in[0];
    const float* w1  = (const float*)d_in[1];
    const float* b1  = (const float*)d_in[2];
    const float* t1  = (const float*)d_in[3];
    const float* w2  = (const float*)d_in[4];
    const float* b2  = (const float*)d_in[5];
    const float* t2  = (const float*)d_in[6];
    const float* fw1 = (const float*)d_in[7];
    const float* fb1 = (const float*)d_in[8];
    const float* fw2 = (const float*)d_in[9];
    const float* fb2 = (const float*)d_in[10];

    float* part = (float*)d_ws;       // [256*96*100] = 9.8 MB

    kb_fused<<<2 * NMC, 256, 0, stream>>>(x, w1, b1, t1, w2, b2, t2, fw1, part);
    kc_out  <<<256, 256, 0, stream>>>(part, fb1, fw2, fb2, (float*)d_out);
}